// Round 5
// baseline (47.574 us; speedup 1.0000x reference)
//
// Fused 3-bit dequant GEMM: C[64,11008] = A[64,4096] @ ((q-4) * s[group])
// R5: single-variable test vs R4 — restore BN=256 so every q row-read is one
// contiguous 1KB wave-instruction (R4's BN=128 gave 512B granules; fills prove
// 7.2 TB/s for sequential streams, we were at ~5.2). Keeps all R4 fixes:
// Apf fragment-order A (contiguous broadcast), LDS double-buffer, rotation
// swizzle (2-way bank = free). LDS 2x32KB -> 2 blocks/CU (64KB in flight/CU).
// Geometry: CB=43 x SB=16 = 688 blocks x 512 thr, KBAND=256, NSTEP=8.
// bf16 partials (22.5MB, L3-resident for the reduce) + reduce kernel.
// Predicted: main 6.5-7 TB/s, total ~38-41 us.

#include <hip/hip_runtime.h>

#define K_ 4096
#define N_ 11008
#define M_ 64
#define SB 16                   // k-split factor
#define CB 43                   // column chunks of BN
#define BK 32                   // k rows per LDS tile
#define BN 256                  // columns per block
#define KBAND (K_ / SB)         // 256
#define NSTEP (KBAND / BK)      // 8

typedef __attribute__((ext_vector_type(8))) short bf16x8;
typedef __attribute__((ext_vector_type(4))) float f32x4;
typedef __attribute__((ext_vector_type(4))) unsigned uint4v;
typedef __attribute__((ext_vector_type(4))) float float4v;
typedef __attribute__((ext_vector_type(4))) unsigned short ushort4v;

static __device__ __forceinline__ unsigned rne_bits(float f) {
  unsigned u = __builtin_bit_cast(unsigned, f);
  return u + 0x7fffu + ((u >> 16) & 1u);   // bf16 in bits [31:16], RNE
}
static __device__ __forceinline__ unsigned pack_bf16(float lo, float hi) {
  return (rne_bits(hi) & 0xffff0000u) | (rne_bits(lo) >> 16);
}
static __device__ __forceinline__ unsigned short bf16_1(float f) {
  return (unsigned short)(rne_bits(f) >> 16);
}

// A (64x4096 f32) -> Apf in MFMA fragment order: Apf[kt][mt][lane] = 8 bf16
// (4 uints). kt=k/32 (128), mt=row-tile (4), lane=64. 512KB total.
__global__ __launch_bounds__(256) void cvtA_frag_kernel(
    const float* __restrict__ A, unsigned* __restrict__ Apf) {
  const int kt = blockIdx.x;          // 0..127
  const int mt = threadIdx.x >> 6;    // 0..3
  const int l  = threadIdx.x & 63;
  const int row = mt * 16 + (l & 15);
  const int kk  = kt * 32 + (l >> 4) * 8;
  const float* ap = A + (size_t)row * K_ + kk;
  uint4v b = { pack_bf16(ap[0], ap[1]), pack_bf16(ap[2], ap[3]),
               pack_bf16(ap[4], ap[5]), pack_bf16(ap[6], ap[7]) };
  *reinterpret_cast<uint4v*>(Apf + ((size_t)(kt * 4 + mt) * 64 + l) * 4) = b;
}

template <bool FROM_FRAG, bool ATOMIC>
__global__ __launch_bounds__(512, 4) void dq_gemm_kernel(
    const int* __restrict__ q, const float* __restrict__ s,
    const unsigned* __restrict__ Apf, const float* __restrict__ Af,
    unsigned short* __restrict__ P, float* __restrict__ out) {
  __shared__ int tile[2][BK * BN];    // 2 x 32KB

  const int tid = threadIdx.x;
  const int l   = tid & 63;
  const int w   = tid >> 6;           // wave 0..7 (owns 32 columns)
  const int fr  = l & 15;
  const int lg  = l >> 4;
  const int cb  = blockIdx.x % CB;    // col chunk fastest -> adjacent blocks
  const int sb  = blockIdx.x / CB;    //   cover contiguous DRAM stretches
  const int n0  = cb * BN;
  const int k0  = sb * KBAND;
  const int cw  = w * 32;

  f32x4 acc[4][2];
  #pragma unroll
  for (int mt = 0; mt < 4; ++mt)
    #pragma unroll
    for (int nt = 0; nt < 2; ++nt)
      acc[mt][nt] = f32x4{0.f, 0.f, 0.f, 0.f};

  // stage [BK][BN] q tile; one full 1KB row per wave-instruction. Per-row
  // rotation rot=8*(row>>3) applied by pre-rotating the per-lane GLOBAL
  // source (global_load_lds writes linearly: dest = base + lane*16).
  auto stage = [&](int buf, int kst) {
    #pragma unroll
    for (int i = 0; i < 4; ++i) {
      const int row = w * 4 + i;                   // wave-uniform
      const int rot = 8 * (row >> 3);
      const int src = (4 * l - rot) & (BN - 1);    // pre-rotated src col (ints)
      const int* gp = q + (size_t)(kst + row) * N_ + n0 + src;
      __builtin_amdgcn_global_load_lds(
          (const __attribute__((address_space(1))) unsigned*)gp,
          (__attribute__((address_space(3))) unsigned*)&tile[buf][row * BN],
          16, 0, 0);
    }
  };

  auto compute = [&](int buf, int kst) {
    const int g = kst >> 6;
    const float sc0 = s[(size_t)g * N_ + n0 + cw + fr];
    const float sc1 = s[(size_t)g * N_ + n0 + cw + 16 + fr];

    bf16x8 af[4];
    #pragma unroll
    for (int mt = 0; mt < 4; ++mt) {
      if constexpr (FROM_FRAG) {
        af[mt] = *reinterpret_cast<const bf16x8*>(
            Apf + ((size_t)((kst >> 5) * 4 + mt) * 64 + l) * 4);
      } else {
        const float* ap = Af + (size_t)(mt * 16 + fr) * K_ + kst + 8 * lg;
        float4v v0 = *reinterpret_cast<const float4v*>(ap);
        float4v v1 = *reinterpret_cast<const float4v*>(ap + 4);
        uint4v b = { pack_bf16(v0[0], v0[1]), pack_bf16(v0[2], v0[3]),
                     pack_bf16(v1[0], v1[1]), pack_bf16(v1[2], v1[3]) };
        af[mt] = __builtin_bit_cast(bf16x8, b);
      }
    }

    const int rot = 8 * lg;             // rows 8lg..8lg+7 share this rotation
    #pragma unroll
    for (int nt = 0; nt < 2; ++nt) {
      const float sc = nt ? sc1 : sc0;
      const float sn = -4.0f * sc;      // fma(q, s, -4s) == (q-4)*s
      const int ci = (cw + nt * 16 + fr + rot) & (BN - 1);
      unsigned pk[4];
      #pragma unroll
      for (int p = 0; p < 4; ++p) {
        const int r0 = 8 * lg + 2 * p;
        const int c0 = tile[buf][r0 * BN + ci];
        const int c1 = tile[buf][(r0 + 1) * BN + ci];
        pk[p] = pack_bf16(fmaf((float)c0, sc, sn), fmaf((float)c1, sc, sn));
      }
      uint4v bv = {pk[0], pk[1], pk[2], pk[3]};
      const bf16x8 bfrag = __builtin_bit_cast(bf16x8, bv);
      #pragma unroll
      for (int mt = 0; mt < 4; ++mt)
        acc[mt][nt] = __builtin_amdgcn_mfma_f32_16x16x32_bf16(
            af[mt], bfrag, acc[mt][nt], 0, 0, 0);
    }
  };

  // ---- K loop: double-buffered, one barrier per step ----
  stage(0, k0);
  __syncthreads();
  for (int st = 0; st < NSTEP; ++st) {
    const int kst = k0 + st * BK;
    if (st + 1 < NSTEP) stage((st + 1) & 1, kst + BK);
    compute(st & 1, kst);
    __syncthreads();   // drains staged loads; guards buffer reuse
  }

  // ---- epilogue: D row = mt*16 + 4*lg + j, col = cw + nt*16 + fr ----
  if constexpr (ATOMIC) {
    #pragma unroll
    for (int mt = 0; mt < 4; ++mt)
      #pragma unroll
      for (int nt = 0; nt < 2; ++nt)
        #pragma unroll
        for (int j = 0; j < 4; ++j)
          atomicAdd(out + (size_t)(mt * 16 + 4 * lg + j) * N_ + n0 + cw +
                        nt * 16 + fr,
                    acc[mt][nt][j]);
  } else {
    unsigned short* Pb = P + (size_t)(cb * SB + sb) * M_ * BN;
    #pragma unroll
    for (int mt = 0; mt < 4; ++mt)
      #pragma unroll
      for (int nt = 0; nt < 2; ++nt)
        #pragma unroll
        for (int j = 0; j < 4; ++j)
          Pb[(mt * 16 + 4 * lg + j) * BN + cw + nt * 16 + fr] =
              bf16_1(acc[mt][nt][j]);
  }
}

// Sum SB bf16 partials -> f32 out. 688 blocks x 256 thr, 4 outputs/thread.
__global__ __launch_bounds__(256) void reduce_kernel(
    const unsigned short* __restrict__ P, float* __restrict__ out) {
  const int flat = blockIdx.x * 256 + threadIdx.x;  // 0 .. 176127
  const int cb = flat >> 12;                        // / 4096 (64*256/4)
  const int r  = flat & 4095;
  const int m  = r >> 6;
  const int cq = (r & 63) * 4;
  const unsigned short* p = P + ((size_t)cb * SB + 0) * M_ * BN + m * BN + cq;
  float s0 = 0.f, s1 = 0.f, s2 = 0.f, s3 = 0.f;
  #pragma unroll
  for (int sb = 0; sb < SB; ++sb) {
    ushort4v v = *reinterpret_cast<const ushort4v*>(p + (size_t)sb * M_ * BN);
    s0 += __builtin_bit_cast(float, (unsigned)v[0] << 16);
    s1 += __builtin_bit_cast(float, (unsigned)v[1] << 16);
    s2 += __builtin_bit_cast(float, (unsigned)v[2] << 16);
    s3 += __builtin_bit_cast(float, (unsigned)v[3] << 16);
  }
  float4v o = {s0, s1, s2, s3};
  *reinterpret_cast<float4v*>(out + (size_t)m * N_ + cb * BN + cq) = o;
}

extern "C" void kernel_launch(void* const* d_in, const int* in_sizes, int n_in,
                              void* d_out, int out_size, void* d_ws, size_t ws_size,
                              hipStream_t stream) {
  const float* A = (const float*)d_in[0];
  const int*   q = (const int*)d_in[1];
  const float* s = (const float*)d_in[2];
  float* out = (float*)d_out;

  const size_t apBytes = (size_t)128 * 4 * 64 * 16;                 // 512 KB
  const size_t pBytes  = (size_t)CB * SB * M_ * BN * sizeof(unsigned short);
  const size_t needFull = apBytes + pBytes;                         // ~23 MB

  if (ws_size >= needFull) {
    unsigned* Apf = (unsigned*)d_ws;
    unsigned short* P = (unsigned short*)((char*)d_ws + apBytes);
    hipLaunchKernelGGL(cvtA_frag_kernel, dim3(128), dim3(256), 0, stream,
                       A, Apf);
    hipLaunchKernelGGL((dq_gemm_kernel<true, false>), dim3(CB * SB), dim3(512),
                       0, stream, q, s, Apf, A, P, out);
    hipLaunchKernelGGL(reduce_kernel, dim3(688), dim3(256), 0, stream, P, out);
  } else if (ws_size >= apBytes) {
    unsigned* Apf = (unsigned*)d_ws;
    hipMemsetAsync(d_out, 0, (size_t)M_ * N_ * sizeof(float), stream);
    hipLaunchKernelGGL(cvtA_frag_kernel, dim3(128), dim3(256), 0, stream,
                       A, Apf);
    hipLaunchKernelGGL((dq_gemm_kernel<true, true>), dim3(CB * SB), dim3(512),
                       0, stream, q, s, Apf, A, (unsigned short*)nullptr, out);
  } else {
    hipMemsetAsync(d_out, 0, (size_t)M_ * N_ * sizeof(float), stream);
    hipLaunchKernelGGL((dq_gemm_kernel<false, true>), dim3(CB * SB), dim3(512),
                       0, stream, q, s, (const unsigned*)nullptr, A,
                       (unsigned short*)nullptr, out);
  }
}

// Round 6
// 44.085 us; speedup vs baseline: 1.0791x; 1.0791x over previous
//
// Fused 3-bit dequant GEMM: C[64,11008] = A[64,4096] @ ((q-4) * s[group])
// R6: kill the per-step vmcnt(0) drain. R4/R5 both ~5.2 TB/s because
// __syncthreads drains all just-issued global_load_lds each step (in-flight
// saw-tooths 64KB->0). Now: NBUF=4 circular LDS pipeline, counted
// s_waitcnt vmcnt(8/4/0) + raw s_barrier + sched_barrier(0) (T3+T4).
// Uniform 4 loads/stage/wave (2 q-dwordx4 + 2 A-frag dword — A staged in LDS
// so the K-loop has zero other vmem; scales preloaded to regs first, so
// in-order vmcnt retirement never forces a pipeline drain).
// Geometry: BK=32, BN=128, CB=86, SB=8, 688 blocks x 512 thr, LDS 80KB ->
// 2 blocks/CU. Rotation swizzle unchanged (2-way bank = free).
// Predicted: main 6.3-7 TB/s (~28-31us), total ~36-40us.

#include <hip/hip_runtime.h>

#define K_ 4096
#define N_ 11008
#define M_ 64
#define SB 8                    // k-split factor
#define CB 86                   // column chunks of BN
#define BK 32                   // k rows per tile
#define BN 128                  // columns per block
#define KBAND (K_ / SB)         // 512
#define NSTEP (KBAND / BK)      // 16
#define NBUF 4

typedef __attribute__((ext_vector_type(8))) short bf16x8;
typedef __attribute__((ext_vector_type(4))) float f32x4;
typedef __attribute__((ext_vector_type(4))) unsigned uint4v;
typedef __attribute__((ext_vector_type(4))) float float4v;
typedef __attribute__((ext_vector_type(4))) unsigned short ushort4v;

static __device__ __forceinline__ unsigned rne_bits(float f) {
  unsigned u = __builtin_bit_cast(unsigned, f);
  return u + 0x7fffu + ((u >> 16) & 1u);   // bf16 in bits [31:16], RNE
}
static __device__ __forceinline__ unsigned pack_bf16(float lo, float hi) {
  return (rne_bits(hi) & 0xffff0000u) | (rne_bits(lo) >> 16);
}
static __device__ __forceinline__ unsigned short bf16_1(float f) {
  return (unsigned short)(rne_bits(f) >> 16);
}

// A (64x4096 f32) -> Apf in MFMA fragment order: Apf[kt][mt][lane] = 8 bf16
// (4 uints). kt=k/32 (128), mt=row-tile (4), lane=64. 512KB total.
__global__ __launch_bounds__(256) void cvtA_frag_kernel(
    const float* __restrict__ A, unsigned* __restrict__ Apf) {
  const int kt = blockIdx.x;          // 0..127
  const int mt = threadIdx.x >> 6;    // 0..3
  const int l  = threadIdx.x & 63;
  const int row = mt * 16 + (l & 15);
  const int kk  = kt * 32 + (l >> 4) * 8;
  const float* ap = A + (size_t)row * K_ + kk;
  uint4v b = { pack_bf16(ap[0], ap[1]), pack_bf16(ap[2], ap[3]),
               pack_bf16(ap[4], ap[5]), pack_bf16(ap[6], ap[7]) };
  *reinterpret_cast<uint4v*>(Apf + ((size_t)(kt * 4 + mt) * 64 + l) * 4) = b;
}

// ---------------- pipelined hot path (requires Apf + P in d_ws) ------------
__global__ __launch_bounds__(512, 4) void dq_gemm_pipe(
    const int* __restrict__ q, const float* __restrict__ s,
    const unsigned* __restrict__ Apf, unsigned short* __restrict__ P) {
  __shared__ int qtile[NBUF][BK * BN];   // 4 x 16KB
  __shared__ int atile[NBUF][1024];      // 4 x 4KB  (Apf[kt] linear copy)

  const int tid = threadIdx.x;
  const int l   = tid & 63;
  const int w   = tid >> 6;           // wave 0..7 (owns 16 columns)
  const int fr  = l & 15;
  const int lg  = l >> 4;
  const int cb  = blockIdx.x % CB;
  const int sb  = blockIdx.x / CB;
  const int n0  = cb * BN;
  const int k0  = sb * KBAND;
  const int cw  = w * 16;

  // --- scales preload FIRST (oldest vmem; retired by the first wait) ---
  float scv[NSTEP / 2];
  #pragma unroll
  for (int g = 0; g < NSTEP / 2; ++g)
    scv[g] = s[(size_t)((k0 >> 6) + g) * N_ + n0 + cw + fr];

  f32x4 acc[4] = {f32x4{0,0,0,0}, f32x4{0,0,0,0}, f32x4{0,0,0,0}, f32x4{0,0,0,0}};

  // stage = exactly 4 uniform loads/wave: 2x q dwordx4 (rotation swizzle via
  // pre-rotated per-lane global source; LDS dest linear) + 2x A-frag dword.
  auto stage = [&](int buf, int kst) {
    #pragma unroll
    for (int i = 0; i < 2; ++i) {
      const int rbase = w * 4 + i * 2;               // wave-uniform row pair
      const int row   = rbase + (l >> 5);
      const int rot   = ((row >> 3) & 3) * 8;
      const int c4    = (4 * l) & 127;
      const int src   = (c4 - rot) & 127;
      const int* gp   = q + (size_t)(kst + row) * N_ + n0 + src;
      __builtin_amdgcn_global_load_lds(
          (const __attribute__((address_space(1))) unsigned*)gp,
          (__attribute__((address_space(3))) unsigned*)&qtile[buf][rbase * BN],
          16, 0, 0);
    }
    const unsigned* ab = Apf + (size_t)(kst >> 5) * 1024 + w * 128;
    #pragma unroll
    for (int i = 0; i < 2; ++i) {
      __builtin_amdgcn_global_load_lds(
          (const __attribute__((address_space(1))) unsigned*)(ab + i * 64 + l),
          (__attribute__((address_space(3))) unsigned*)&atile[buf][w * 128 + i * 64],
          4, 0, 0);
    }
  };

  auto compute = [&](int buf, float sc) {
    bf16x8 af[4];
    #pragma unroll
    for (int mt = 0; mt < 4; ++mt)
      af[mt] = *reinterpret_cast<const bf16x8*>(&atile[buf][mt * 256 + l * 4]);
    const float sn = -4.0f * sc;                     // fma(q, s, -4s)
    const int rot = 8 * lg;
    const int ci  = (cw + fr + rot) & 127;
    unsigned pk[4];
    #pragma unroll
    for (int p = 0; p < 4; ++p) {
      const int r0 = 8 * lg + 2 * p;
      const int c0 = qtile[buf][r0 * BN + ci];
      const int c1 = qtile[buf][(r0 + 1) * BN + ci];
      pk[p] = pack_bf16(fmaf((float)c0, sc, sn), fmaf((float)c1, sc, sn));
    }
    uint4v bv = {pk[0], pk[1], pk[2], pk[3]};
    const bf16x8 bfrag = __builtin_bit_cast(bf16x8, bv);
    #pragma unroll
    for (int mt = 0; mt < 4; ++mt)
      acc[mt] = __builtin_amdgcn_mfma_f32_16x16x32_bf16(af[mt], bfrag, acc[mt],
                                                        0, 0, 0);
  };

  // ---- prologue: 3 tiles in flight (12 loads) ----
  stage(0, k0);
  stage(1, k0 + BK);
  stage(2, k0 + 2 * BK);

  // ---- steady state: wait keeps >=2 tiles in flight, never drains to 0.
  // Outstanding before wait = 12 loads (3 stages); vmcnt(8) retires tile st.
  // Fully unrolled so scv[] and buf indices are compile-time (rule #20).
  #pragma unroll
  for (int st = 0; st < NSTEP - 2; ++st) {
    asm volatile("s_waitcnt vmcnt(8)" ::: "memory");
    __builtin_amdgcn_s_barrier();
    __builtin_amdgcn_sched_barrier(0);   // pin ds_reads below the barrier
    compute(st & 3, scv[st >> 1]);
    if (st + 3 < NSTEP) stage((st + 3) & 3, k0 + (st + 3) * BK);
  }
  // ---- tail: two peeled steps ----
  asm volatile("s_waitcnt vmcnt(4)" ::: "memory");
  __builtin_amdgcn_s_barrier();
  __builtin_amdgcn_sched_barrier(0);
  compute((NSTEP - 2) & 3, scv[(NSTEP - 2) >> 1]);

  asm volatile("s_waitcnt vmcnt(0)" ::: "memory");
  __builtin_amdgcn_s_barrier();
  __builtin_amdgcn_sched_barrier(0);
  compute((NSTEP - 1) & 3, scv[(NSTEP - 1) >> 1]);

  // ---- epilogue: D row = mt*16 + 4*lg + j, col = cw + fr ----
  unsigned short* Pb = P + (size_t)(cb * SB + sb) * M_ * BN;
  #pragma unroll
  for (int mt = 0; mt < 4; ++mt)
    #pragma unroll
    for (int j = 0; j < 4; ++j)
      Pb[(mt * 16 + 4 * lg + j) * BN + cw + fr] = bf16_1(acc[mt][j]);
}

// Sum SB bf16 partials -> f32 out. 688 blocks x 256 thr, 4 outputs/thread.
__global__ __launch_bounds__(256) void reduce_kernel(
    const unsigned short* __restrict__ P, float* __restrict__ out) {
  const int flat = blockIdx.x * 256 + threadIdx.x;  // 0 .. 176127
  const int cb = flat >> 11;                        // / 2048
  const int r  = flat & 2047;
  const int m  = r >> 5;
  const int cq = (r & 31) * 4;
  const unsigned short* p = P + ((size_t)cb * SB * M_ + m) * BN + cq;
  float s0 = 0.f, s1 = 0.f, s2 = 0.f, s3 = 0.f;
  #pragma unroll
  for (int sb = 0; sb < SB; ++sb) {
    ushort4v v = *reinterpret_cast<const ushort4v*>(p + (size_t)sb * M_ * BN);
    s0 += __builtin_bit_cast(float, (unsigned)v[0] << 16);
    s1 += __builtin_bit_cast(float, (unsigned)v[1] << 16);
    s2 += __builtin_bit_cast(float, (unsigned)v[2] << 16);
    s3 += __builtin_bit_cast(float, (unsigned)v[3] << 16);
  }
  float4v o = {s0, s1, s2, s3};
  *reinterpret_cast<float4v*>(out + (size_t)m * N_ + cb * BN + cq) = o;
}

// ---------------- fallback (ws too small): R4-style, atomic epilogue -------
__global__ __launch_bounds__(512, 8) void dq_gemm_basic(
    const int* __restrict__ q, const float* __restrict__ s,
    const float* __restrict__ Af, float* __restrict__ out) {
  __shared__ int tile[2][BK * BN];

  const int tid = threadIdx.x;
  const int l   = tid & 63;
  const int w   = tid >> 6;
  const int fr  = l & 15;
  const int lg  = l >> 4;
  const int cb  = blockIdx.x % CB;
  const int sb  = blockIdx.x / CB;
  const int n0  = cb * BN;
  const int k0  = sb * KBAND;
  const int cw  = w * 16;

  f32x4 acc[4] = {f32x4{0,0,0,0}, f32x4{0,0,0,0}, f32x4{0,0,0,0}, f32x4{0,0,0,0}};

  auto stage = [&](int buf, int kst) {
    #pragma unroll
    for (int i = 0; i < 2; ++i) {
      const int rbase = w * 4 + i * 2;
      const int row   = rbase + (l >> 5);
      const int rot   = ((row >> 3) & 3) * 8;
      const int c4    = (4 * l) & 127;
      const int src   = (c4 - rot) & 127;
      const int* gp   = q + (size_t)(kst + row) * N_ + n0 + src;
      __builtin_amdgcn_global_load_lds(
          (const __attribute__((address_space(1))) unsigned*)gp,
          (__attribute__((address_space(3))) unsigned*)&tile[buf][rbase * BN],
          16, 0, 0);
    }
  };

  auto compute = [&](int buf, int kst) {
    const float sc = s[(size_t)(kst >> 6) * N_ + n0 + cw + fr];
    bf16x8 af[4];
    #pragma unroll
    for (int mt = 0; mt < 4; ++mt) {
      const float* ap = Af + (size_t)(mt * 16 + fr) * K_ + kst + 8 * lg;
      float4v v0 = *reinterpret_cast<const float4v*>(ap);
      float4v v1 = *reinterpret_cast<const float4v*>(ap + 4);
      uint4v b = { pack_bf16(v0[0], v0[1]), pack_bf16(v0[2], v0[3]),
                   pack_bf16(v1[0], v1[1]), pack_bf16(v1[2], v1[3]) };
      af[mt] = __builtin_bit_cast(bf16x8, b);
    }
    const float sn = -4.0f * sc;
    const int rot = 8 * lg;
    const int ci  = (cw + fr + rot) & 127;
    unsigned pk[4];
    #pragma unroll
    for (int p = 0; p < 4; ++p) {
      const int r0 = 8 * lg + 2 * p;
      const int c0 = tile[buf][r0 * BN + ci];
      const int c1 = tile[buf][(r0 + 1) * BN + ci];
      pk[p] = pack_bf16(fmaf((float)c0, sc, sn), fmaf((float)c1, sc, sn));
    }
    uint4v bv = {pk[0], pk[1], pk[2], pk[3]};
    const bf16x8 bfrag = __builtin_bit_cast(bf16x8, bv);
    #pragma unroll
    for (int mt = 0; mt < 4; ++mt)
      acc[mt] = __builtin_amdgcn_mfma_f32_16x16x32_bf16(af[mt], bfrag, acc[mt],
                                                        0, 0, 0);
  };

  stage(0, k0);
  __syncthreads();
  for (int st = 0; st < NSTEP; ++st) {
    const int kst = k0 + st * BK;
    if (st + 1 < NSTEP) stage((st + 1) & 1, kst + BK);
    compute(st & 1, kst);
    __syncthreads();
  }

  #pragma unroll
  for (int mt = 0; mt < 4; ++mt)
    #pragma unroll
    for (int j = 0; j < 4; ++j)
      atomicAdd(out + (size_t)(mt * 16 + 4 * lg + j) * N_ + n0 + cw + fr,
                acc[mt][j]);
}

extern "C" void kernel_launch(void* const* d_in, const int* in_sizes, int n_in,
                              void* d_out, int out_size, void* d_ws, size_t ws_size,
                              hipStream_t stream) {
  const float* A = (const float*)d_in[0];
  const int*   q = (const int*)d_in[1];
  const float* s = (const float*)d_in[2];
  float* out = (float*)d_out;

  const size_t apBytes = (size_t)128 * 1024 * sizeof(unsigned);      // 512 KB
  const size_t pBytes  = (size_t)CB * SB * M_ * BN * sizeof(unsigned short);
  const size_t needFull = apBytes + pBytes;                          // ~11.8 MB

  if (ws_size >= needFull) {
    unsigned* Apf = (unsigned*)d_ws;
    unsigned short* P = (unsigned short*)((char*)d_ws + apBytes);
    hipLaunchKernelGGL(cvtA_frag_kernel, dim3(128), dim3(256), 0, stream,
                       A, Apf);
    hipLaunchKernelGGL(dq_gemm_pipe, dim3(CB * SB), dim3(512), 0, stream,
                       q, s, Apf, P);
    hipLaunchKernelGGL(reduce_kernel, dim3(688), dim3(256), 0, stream, P, out);
  } else {
    hipMemsetAsync(d_out, 0, (size_t)M_ * N_ * sizeof(float), stream);
    hipLaunchKernelGGL(dq_gemm_basic, dim3(CB * SB), dim3(512), 0, stream,
                       q, s, A, out);
  }
}